// Round 13
// baseline (109.795 us; speedup 1.0000x reference)
//
#include <hip/hip_runtime.h>
#include <stdint.h>

// NormalizedLoss: batched chamfer + coverage/quality on point clouds.
// x: [32, 2048, 3] fp32, y: [32, 2048, 3] fp32 -> out: [val, cd, cov, qual] fp32.
//
// R13: MFMA reformulation. 12 rounds of VALU-side levers left nn pinned at
// ~40us (4x static floor, invariant to occupancy/VGPR/packed-asm). Move the
// pair work to the (idle) matrix pipe: d[q,p] = qn + pn - 2 q.p computed by
// mfma_f32_16x16x32_bf16 with everything packed into K (15 of 32 slots):
//   A row: qh0..2, ql0..2, qh0..2, qnh,qnm,qnl, 1,1,1     (q = row side)
//   B row: -2ph x3, -2ph x3, -2pl x3, 1,1,1, pnh,pnm,pnl  (p = col side)
// bf16xbf16 products are exact in fp32; dropped term 2*ql*pl ~3e-5; 3-way
// split norms ~1e-6 -> d error ~3e-5, under the existing 1e-3 EMB noise.
// Epilogue per 16x16 tile: embed row index (quad*4+reg, disjoint bits) via
// v_and_or, min3 chain into best[p-tile]; cross-quad shfl_xor at the end.
// pack_kernel pre-packs per-point A/B rows (64B, upper half zeros) in ws.

#define BB 32
#define NP 2048
#define BIGF 1e10f

typedef unsigned int u32;
typedef unsigned short u16;
typedef __bf16 bf16x8 __attribute__((ext_vector_type(8)));
typedef float f32x4 __attribute__((ext_vector_type(4)));

__device__ __forceinline__ u16 bf16rne(float f) {  // round-to-nearest-even
  u32 u = __float_as_uint(f);
  return (u16)((u + 0x7FFFu + ((u >> 16) & 1u)) >> 16);
}
__device__ __forceinline__ float bf2f(u16 h) { return __uint_as_float((u32)h << 16); }
__device__ __forceinline__ u32 pk2(u16 a, u16 b) { return (u32)a | ((u32)b << 16); }

// One thread per point (2 clouds x 65536). Writes 64B A-row + 64B B-row.
__global__ __launch_bounds__(256) void pack_kernel(const float* __restrict__ x,
                                                   const float* __restrict__ y,
                                                   u16* __restrict__ ap,
                                                   u16* __restrict__ bp) {
  int t = blockIdx.x * 256 + threadIdx.x;  // row index: cloud*65536 + g
  int cloud = t >> 16;
  int g = t & 65535;
  const float* src = (cloud ? y : x) + 3 * g;
  float v[3] = {src[0], src[1], src[2]};
  float n = v[0] * v[0] + v[1] * v[1] + v[2] * v[2];
  if (v[0] + v[1] + v[2] == 0.0f) n += BIGF;  // invalid row: out of every min

  u16 h[3], l[3], mh[3], ml[3];
#pragma unroll
  for (int i = 0; i < 3; ++i) {
    h[i] = bf16rne(v[i]);
    l[i] = bf16rne(v[i] - bf2f(h[i]));
    float m = -2.0f * v[i];
    mh[i] = bf16rne(m);
    ml[i] = bf16rne(m - bf2f(mh[i]));
  }
  u16 nh = bf16rne(n);
  float r1 = n - bf2f(nh);
  u16 nm = bf16rne(r1);
  u16 nl = bf16rne(r1 - bf2f(nm));
  const u16 ONE = 0x3F80;

  uint4* a4 = (uint4*)(ap + (size_t)t * 32);  // 32 u16 = 64B row
  uint4* b4 = (uint4*)(bp + (size_t)t * 32);
  // A slots 0..15: h0 h1 h2 l0 l1 l2 h0 h1 | h2 nh nm nl ONE ONE ONE 0
  a4[0] = make_uint4(pk2(h[0], h[1]), pk2(h[2], l[0]), pk2(l[1], l[2]), pk2(h[0], h[1]));
  a4[1] = make_uint4(pk2(h[2], nh), pk2(nm, nl), pk2(ONE, ONE), pk2(ONE, 0));
  a4[2] = make_uint4(0, 0, 0, 0);  // K slots 16..31 = 0
  a4[3] = make_uint4(0, 0, 0, 0);
  // B slots 0..15: mh0 mh1 mh2 mh0 mh1 mh2 ml0 ml1 | ml2 ONE ONE ONE nh nm nl 0
  b4[0] = make_uint4(pk2(mh[0], mh[1]), pk2(mh[2], mh[0]), pk2(mh[1], mh[2]), pk2(ml[0], ml[1]));
  b4[1] = make_uint4(pk2(ml[2], ONE), pk2(ONE, ONE), pk2(nh, nm), pk2(nl, 0));
  b4[2] = make_uint4(0, 0, 0, 0);
  b4[3] = make_uint4(0, 0, 0, 0);
}

__global__ __launch_bounds__(512, 4) void nn_kernel(const u16* __restrict__ ap,
                                                    const u16* __restrict__ bp,
                                                    const float* __restrict__ x,
                                                    const float* __restrict__ y,
                                                    u32* __restrict__ hitpart,
                                                    float* __restrict__ sums_part,
                                                    float* __restrict__ cnts_part) {
  int bid = blockIdx.x;  // 512 blocks: side(1)|b(5)|pc(3); block = 256 p x 2048 q
  int side = bid >> 8;
  int b = (bid >> 3) & 31;
  int pc = bid & 7;
  int tid = threadIdx.x;
  int w = __builtin_amdgcn_readfirstlane(tid >> 6);  // 0..7, wave-uniform
  int lane = tid & 63;
  int quad = lane >> 4, m16 = lane & 15;

  __shared__ u32 merged[8][256];  // per-wave embedded (d|idx) partials
  __shared__ u32 hitlds[64];
  __shared__ float redc[4], redn[4];

  int cloudA = side ^ 1;  // side0: A(row/q)=y, B(col/p)=x
  int cloudB = side;
  const uint4* a4 = (const uint4*)ap;  // row r -> a4[r*4 + quad] = 8 bf16 K-slice
  const uint4* b4 = (const uint4*)bp;

  // ---- resident B fragments: 16 p-tiles x 4 VGPR ----
  bf16x8 Bf[16];
#pragma unroll
  for (int pt = 0; pt < 16; ++pt) {
    int rowB = cloudB * 65536 + b * 2048 + pc * 256 + pt * 16 + m16;
    Bf[pt] = __builtin_bit_cast(bf16x8, b4[rowB * 4 + quad]);
  }
  float best[16];
#pragma unroll
  for (int pt = 0; pt < 16; ++pt) best[pt] = 3.0e38f;
  if (tid < 64) hitlds[tid] = 0u;

  // ---- main loop: wave's 16 q-tiles (q-range w*256..), A 1-deep prefetch ----
  int rowA0 = cloudA * 65536 + b * 2048 + w * 256 + m16;
  u32 jq = (u32)(quad * 4);  // row-within-tile bits 2..3
  f32x4 zc = {0.f, 0.f, 0.f, 0.f};
  uint4 araw = a4[rowA0 * 4 + quad];
  for (int qt = 0; qt < 16; ++qt) {
    uint4 anext = a4[(rowA0 + ((qt + 1) & 15) * 16) * 4 + quad];  // wraps, unused last
    bf16x8 Af = __builtin_bit_cast(bf16x8, araw);
    u32 jtq = (u32)(w * 256 + qt * 16) + jq;  // global q row of reg 0
#pragma unroll
    for (int pt = 0; pt < 16; ++pt) {
      f32x4 d = __builtin_amdgcn_mfma_f32_16x16x32_bf16(Af, Bf[pt], zc, 0, 0, 0);
      u32 e0 = (__float_as_uint(d[0]) & 0xFFFFF800u) | jtq;
      u32 e1 = (__float_as_uint(d[1]) & 0xFFFFF800u) | (jtq + 1);
      u32 e2 = (__float_as_uint(d[2]) & 0xFFFFF800u) | (jtq + 2);
      u32 e3 = (__float_as_uint(d[3]) & 0xFFFFF800u) | (jtq + 3);
      float m01 = fminf(__uint_as_float(e0), __uint_as_float(e1));
      float m23 = fminf(__uint_as_float(e2), __uint_as_float(e3));
      best[pt] = fminf(best[pt], fminf(m01, m23));
    }
    araw = anext;
  }

  // ---- cross-quad reduce: lanes {c,c+16,c+32,c+48} hold partials of col c ----
#pragma unroll
  for (int pt = 0; pt < 16; ++pt) {
    float v = best[pt];
    v = fminf(v, __shfl_xor(v, 16, 64));
    v = fminf(v, __shfl_xor(v, 32, 64));
    if (lane < 16) merged[w][pt * 16 + lane] = __float_as_uint(v);
  }
  __syncthreads();

  // ---- merge 8 wave partials; d already = full distance (qn+pn-2qp) ----
  float contrib = 0.f, cnt = 0.f;
  if (tid < 256) {
    float bd = __uint_as_float(merged[0][tid]);
#pragma unroll
    for (int ww = 1; ww < 8; ++ww) bd = fminf(bd, __uint_as_float(merged[ww][tid]));
    u32 bits = __float_as_uint(bd);
    u32 bi = bits & 0x7FFu;                            // argmin q index
    float dmin = __uint_as_float(bits & 0xFFFFF800u);  // truncated min d
    const float* praw = (side ? y : x) + (b * NP + pc * 256 + tid) * 3;
    float p0 = praw[0], p1 = praw[1], p2 = praw[2];
    bool valid = (p0 + p1 + p2) != 0.f;
    contrib = valid ? dmin : 0.f;
    cnt = valid ? 1.f : 0.f;
    if (valid) atomicOr(&hitlds[bi >> 5], 1u << (bi & 31));
  }
  for (int o = 32; o > 0; o >>= 1) {
    contrib += __shfl_down(contrib, o, 64);
    cnt += __shfl_down(cnt, o, 64);
  }
  if (tid < 256 && lane == 0) { redc[tid >> 6] = contrib; redn[tid >> 6] = cnt; }
  __syncthreads();
  if (tid == 0) {
    sums_part[bid] = redc[0] + redc[1] + redc[2] + redc[3];
    cnts_part[bid] = redn[0] + redn[1] + redn[2] + redn[3];
  }
  if (tid < 64) hitpart[bid * 64 + tid] = hitlds[tid];
}

// One block, 512 threads: 8 threads per (side,b); OR 8 pc-partials, popcount,
// sum part sums/cnts, then one wave assembles the 4 scalars.
__global__ __launch_bounds__(512) void assemble_kernel(const u32* __restrict__ hitpart,
                                                       const float* __restrict__ sums_part,
                                                       const float* __restrict__ cnts_part,
                                                       float* __restrict__ out) {
  __shared__ float hs[64], ss[64], cs[64];
  int tid = threadIdx.x;
  int sb = tid >> 3, c = tid & 7;  // sb = side*32+b; part bid = sb*8 + pc
  float h = 0.f;
  for (int wd = c; wd < 64; wd += 8) {
    u32 m = 0u;
#pragma unroll
    for (int blk = 0; blk < 8; ++blk) m |= hitpart[(sb * 8 + blk) * 64 + wd];
    h += (float)__popc(m);
  }
  h += __shfl_down(h, 4, 8);
  h += __shfl_down(h, 2, 8);
  h += __shfl_down(h, 1, 8);
  if (c == 0) {
    float s = 0.f, n = 0.f;
#pragma unroll
    for (int blk = 0; blk < 8; ++blk) {
      s += sums_part[sb * 8 + blk];
      n += cnts_part[sb * 8 + blk];
    }
    hs[sb] = h; ss[sb] = s; cs[sb] = n;
  }
  __syncthreads();
  if (tid < 64) {
    float cd = 0.f, cov = 0.f, qual = 0.f;
    if (tid < BB) {
      float nx = cs[tid], ny = cs[BB + tid];
      cd = ss[tid] / nx + ss[BB + tid] / ny;
      cov = hs[tid] / ny;        // side0 (p=x) hits y indices: /ny
      qual = hs[BB + tid] / nx;  // side1 (p=y) hits x indices: /nx
    }
    for (int o = 32; o > 0; o >>= 1) {
      cd += __shfl_down(cd, o, 64);
      cov += __shfl_down(cov, o, 64);
      qual += __shfl_down(qual, o, 64);
    }
    if (tid == 0) {
      cd /= (float)BB; cov /= (float)BB; qual /= (float)BB;
      out[0] = cd - 1e-4f * cov - 1e-4f * qual;  // WCD*cd - WCOV*cov - WQUAL*qual
      out[1] = cd;
      out[2] = cov;
      out[3] = qual;
    }
  }
}

extern "C" void kernel_launch(void* const* d_in, const int* in_sizes, int n_in,
                              void* d_out, int out_size, void* d_ws, size_t ws_size,
                              hipStream_t stream) {
  const float* x = (const float*)d_in[0];
  const float* y = (const float*)d_in[1];
  float* out = (float*)d_out;
  char* ws = (char*)d_ws;

  // ws layout (all regions fully written by producers; no memset needed):
  //   [0, 128KB)        hitpart: 512 blocks x 64 u32
  //   [128KB, +2KB)     sums_part: 512 f32
  //   [130KB, +2KB)     cnts_part: 512 f32
  //   [132KB, +8MB)     ap: 131072 rows x 64B packed A-rows
  //   [132KB+8MB, +8MB) bp: 131072 rows x 64B packed B-rows
  u32* hitpart = (u32*)ws;
  float* sums_part = (float*)(ws + 131072);
  float* cnts_part = (float*)(ws + 133120);
  u16* ap = (u16*)(ws + 135168);
  u16* bp = (u16*)(ws + 135168 + 8388608ull);

  pack_kernel<<<512, 256, 0, stream>>>(x, y, ap, bp);
  nn_kernel<<<512, 512, 0, stream>>>(ap, bp, x, y, hitpart, sums_part, cnts_part);
  assemble_kernel<<<1, 512, 0, stream>>>(hitpart, sums_part, cnts_part, out);
}

// Round 14
// 91.637 us; speedup vs baseline: 1.1982x; 1.1982x over previous
//
#include <hip/hip_runtime.h>
#include <stdint.h>

// NormalizedLoss: batched chamfer + coverage/quality on point clouds.
// x: [32, 2048, 3] fp32, y: [32, 2048, 3] fp32 -> out: [val, cd, cov, qual] fp32.
//
// R14: halve the LDS-broadcast instruction count (the ~14us pipe floor behind
// the ~33us R11 plateau) via P=8 per lane WITHOUT duplicated p operands:
//  - p stored as natural pairs (-2p_even,-2p_odd): 24 VGPR for 8 p
//  - per q-record, also form swapped q (q1,q0) (2 movs/component, amortized):
//      dA = pk_fma(q,  p_pair, ...) = (d[q0,p0], d[q1,p1])
//      dB = pk_fma(qs, p_pair, ...) = (d[q1,p0], d[q0,p1])
//    -> 16 cells per 2 ds_read_b128 (2x R11), ~3.5 VALU/cell (~12us static),
//       LDS pipe ~7us. Grid 1024 (pc x qc quarters) = 4 blocks/CU = 32
//       waves/CU (max TLP, R11-proven). launch_bounds(512,8) caps VGPR 64.

#define BB 32
#define NP 2048
#define BIGF 1e10f

typedef unsigned int u32;
typedef float f2 __attribute__((ext_vector_type(2)));

// embed 11-bit global q-index in the mantissa: float order ~ (d, idx) lex
#define EMB(d, jg) __uint_as_float((__float_as_uint(d) & 0xFFFFF800u) | (jg))

__device__ __forceinline__ f2 pk_fma(f2 a, f2 b, f2 c) {
  f2 d;
  asm("v_pk_fma_f32 %0, %1, %2, %3" : "=v"(d) : "v"(a), "v"(b), "v"(c));
  return d;
}
__device__ __forceinline__ float min3(float a, float b, float c) {
  float r;
  asm("v_min3_f32 %0, %1, %2, %3" : "=v"(r) : "v"(a), "v"(b), "v"(c));
  return r;
}

__global__ __launch_bounds__(512, 8) void nn_kernel(const float* __restrict__ x,
                                                    const float* __restrict__ y,
                                                    u32* __restrict__ part) {
  int bid = blockIdx.x;  // 1024 blocks: side(1)|b(5)|pc(2)|qc(2); 512p x 512q
  int side = bid >> 9;
  int b = (bid >> 4) & 31;
  int pc = (bid >> 2) & 3;
  int qc = bid & 3;
  int tid = threadIdx.x;
  int w = __builtin_amdgcn_readfirstlane(tid >> 6);  // 0..7, wave-uniform
  int lane = tid & 63;

  __shared__ float4 qs[512];      // 8KB; rec r -> qs[2r]=(x0,x1,y0,y1), qs[2r+1]=(z0,z1,n0,n1)
  __shared__ u32 merged[8][512];  // 16KB per-wave embedded (d|idx) partials

  // ---- stage this block's 512 q (qc quarter) as 256 pair-records ----
  if (tid < 256) {
    const float* qraw = (side ? x : y) + (b * NP + qc * 512) * 3 + tid * 6;
    f2 a01 = *(const f2*)(qraw);      // x0,y0
    f2 a23 = *(const f2*)(qraw + 2);  // z0,x1
    f2 a45 = *(const f2*)(qraw + 4);  // y1,z1
    float q0x = a01.x, q0y = a01.y, q0z = a23.x;
    float q1x = a23.y, q1y = a45.x, q1z = a45.y;
    float n0 = q0x * q0x + q0y * q0y + q0z * q0z;
    float n1 = q1x * q1x + q1y * q1y + q1z * q1z;
    if (q0x + q0y + q0z == 0.f) n0 += BIGF;  // invalid rows out of every min
    if (q1x + q1y + q1z == 0.f) n1 += BIGF;
    qs[2 * tid]     = make_float4(q0x, q1x, q0y, q1y);
    qs[2 * tid + 1] = make_float4(q0z, q1z, n0, n1);
  }

  // ---- p prologue: every wave loads the SAME 512 p; pairs, NOT duplicated ----
  const float* praw = (side ? y : x) + (b * NP + pc * 512) * 3;
  f2 pmx[4], pmy[4], pmz[4];  // pair pp covers p_local (lane+128pp, lane+128pp+64)
  float best[8];
#pragma unroll
  for (int pp = 0; pp < 4; ++pp) {
    int pl0 = lane + 128 * pp;       // even member  (k = 2pp)
    int pl1 = lane + 128 * pp + 64;  // odd member   (k = 2pp+1)
    pmx[pp] = (f2){-2.f * praw[3 * pl0], -2.f * praw[3 * pl1]};
    pmy[pp] = (f2){-2.f * praw[3 * pl0 + 1], -2.f * praw[3 * pl1 + 1]};
    pmz[pp] = (f2){-2.f * praw[3 * pl0 + 2], -2.f * praw[3 * pl1 + 2]};
    best[2 * pp] = 3.0e38f;
    best[2 * pp + 1] = 3.0e38f;
  }
  __syncthreads();

  // ---- inner loop: wave's 32 records (64 q) vs its 8 p-points ----
  const float4* qr = &qs[w * 64];
  u32 je = (u32)(qc * 512 + w * 64);  // global q index of this wave's record 0
#pragma unroll 4
  for (int r = 0; r < 32; ++r) {
    float4 A = qr[2 * r];      // wave-uniform ds_read_b128 (broadcast)
    float4 B = qr[2 * r + 1];
    f2 qx = (f2){A.x, A.y}, qxs = (f2){A.y, A.x};   // swapped forms: 2 movs each
    f2 qy = (f2){A.z, A.w}, qys = (f2){A.w, A.z};
    f2 qz = (f2){B.x, B.y}, qzs = (f2){B.y, B.x};
    f2 qw = (f2){B.z, B.w}, qws = (f2){B.w, B.z};
    u32 j0 = je + 2 * (u32)r, j1 = j0 + 1;
#pragma unroll
    for (int pp = 0; pp < 4; ++pp) {
      // dA = (d[q0,pe], d[q1,po]) ; dB = (d[q1,pe], d[q0,po])
      f2 dA = pk_fma(qx, pmx[pp], pk_fma(qy, pmy[pp], pk_fma(qz, pmz[pp], qw)));
      f2 dB = pk_fma(qxs, pmx[pp], pk_fma(qys, pmy[pp], pk_fma(qzs, pmz[pp], qws)));
      best[2 * pp]     = min3(best[2 * pp],     EMB(dA.x, j0), EMB(dB.x, j1));
      best[2 * pp + 1] = min3(best[2 * pp + 1], EMB(dB.y, j0), EMB(dA.y, j1));
    }
  }

  // p_local of best[k]: lane + 64*( (k&1) + 2*(k>>1) )? No: pair pp covers
  // pl0 = lane+128pp (k=2pp) and pl1 = lane+128pp+64 (k=2pp+1) -> pl = lane + 64*k'
  // with k' = 2pp + (odd) mapped as: best[2pp] -> lane+128pp, best[2pp+1] -> lane+128pp+64.
#pragma unroll
  for (int pp = 0; pp < 4; ++pp) {
    merged[w][lane + 128 * pp]      = __float_as_uint(best[2 * pp]);
    merged[w][lane + 128 * pp + 64] = __float_as_uint(best[2 * pp + 1]);
  }
  __syncthreads();

  // ---- merge 8 wave partials; store embedded u32 per p ----
  {
    float bd = __uint_as_float(merged[0][tid]);
#pragma unroll
    for (int ww = 1; ww < 8; ++ww) bd = fminf(bd, __uint_as_float(merged[ww][tid]));
    // part[qc][side*65536 + b*2048 + pc*512 + tid]
    part[qc * 131072 + side * 65536 + b * 2048 + pc * 512 + tid] = __float_as_uint(bd);
  }
}

// 256 blocks x 512 thr: combine 4 qc quarters, recompute pn/validity, scatter
// hits into a block-local bitmask, reduce sums/cnts per block.
__global__ __launch_bounds__(512) void merge_kernel(const float* __restrict__ x,
                                                    const float* __restrict__ y,
                                                    const u32* __restrict__ part,
                                                    u32* __restrict__ hitpart,
                                                    float* __restrict__ sums_part,
                                                    float* __restrict__ cnts_part) {
  int bid = blockIdx.x;  // 256: side(1)|b(5)|pc(2)
  int side = bid >> 7;
  int b = (bid >> 2) & 31;
  int pc = bid & 3;
  int tid = threadIdx.x;
  int lane = tid & 63, w = tid >> 6;

  __shared__ u32 hitlds[64];
  __shared__ float redc[8], redn[8];
  if (tid < 64) hitlds[tid] = 0u;
  __syncthreads();

  int pidx = side * 65536 + b * 2048 + pc * 512 + tid;
  float bd = fminf(fminf(__uint_as_float(part[pidx]), __uint_as_float(part[131072 + pidx])),
                   fminf(__uint_as_float(part[262144 + pidx]), __uint_as_float(part[393216 + pidx])));
  u32 bits = __float_as_uint(bd);
  u32 bi = bits & 0x7FFu;                            // global q index
  float dmin = __uint_as_float(bits & 0xFFFFF800u);  // truncated min d'
  const float* praw = (side ? y : x) + (b * NP + pc * 512 + tid) * 3;
  float p0 = praw[0], p1 = praw[1], p2 = praw[2];
  bool valid = (p0 + p1 + p2) != 0.f;
  float contrib = valid ? (dmin + p0 * p0 + p1 * p1 + p2 * p2) : 0.f;
  float cnt = valid ? 1.f : 0.f;
  if (valid) atomicOr(&hitlds[bi >> 5], 1u << (bi & 31));

  for (int o = 32; o > 0; o >>= 1) {
    contrib += __shfl_down(contrib, o, 64);
    cnt += __shfl_down(cnt, o, 64);
  }
  if (lane == 0) { redc[w] = contrib; redn[w] = cnt; }
  __syncthreads();
  if (tid == 0) {
    sums_part[bid] = redc[0] + redc[1] + redc[2] + redc[3] + redc[4] + redc[5] + redc[6] + redc[7];
    cnts_part[bid] = redn[0] + redn[1] + redn[2] + redn[3] + redn[4] + redn[5] + redn[6] + redn[7];
  }
  if (tid < 64) hitpart[bid * 64 + tid] = hitlds[tid];
}

// One block, 512 threads: 8 threads per (side,b); OR 4 pc-partials, popcount,
// sum part sums/cnts, then one wave assembles the 4 scalars.
__global__ __launch_bounds__(512) void assemble_kernel(const u32* __restrict__ hitpart,
                                                       const float* __restrict__ sums_part,
                                                       const float* __restrict__ cnts_part,
                                                       float* __restrict__ out) {
  __shared__ float hs[64], ss[64], cs[64];
  int tid = threadIdx.x;
  int sb = tid >> 3, c = tid & 7;  // sb = side*32+b; part bid = sb*4 + pc
  float h = 0.f;
  for (int wd = c; wd < 64; wd += 8) {
    u32 m = 0u;
#pragma unroll
    for (int blk = 0; blk < 4; ++blk) m |= hitpart[(sb * 4 + blk) * 64 + wd];
    h += (float)__popc(m);
  }
  h += __shfl_down(h, 4, 8);
  h += __shfl_down(h, 2, 8);
  h += __shfl_down(h, 1, 8);
  if (c == 0) {
    float s = 0.f, n = 0.f;
#pragma unroll
    for (int blk = 0; blk < 4; ++blk) {
      s += sums_part[sb * 4 + blk];
      n += cnts_part[sb * 4 + blk];
    }
    hs[sb] = h; ss[sb] = s; cs[sb] = n;
  }
  __syncthreads();
  if (tid < 64) {
    float cd = 0.f, cov = 0.f, qual = 0.f;
    if (tid < BB) {
      float nx = cs[tid], ny = cs[BB + tid];
      cd = ss[tid] / nx + ss[BB + tid] / ny;
      cov = hs[tid] / ny;        // side0 (p=x) hits y indices: /ny
      qual = hs[BB + tid] / nx;  // side1 (p=y) hits x indices: /nx
    }
    for (int o = 32; o > 0; o >>= 1) {
      cd += __shfl_down(cd, o, 64);
      cov += __shfl_down(cov, o, 64);
      qual += __shfl_down(qual, o, 64);
    }
    if (tid == 0) {
      cd /= (float)BB; cov /= (float)BB; qual /= (float)BB;
      out[0] = cd - 1e-4f * cov - 1e-4f * qual;  // WCD*cd - WCOV*cov - WQUAL*qual
      out[1] = cd;
      out[2] = cov;
      out[3] = qual;
    }
  }
}

extern "C" void kernel_launch(void* const* d_in, const int* in_sizes, int n_in,
                              void* d_out, int out_size, void* d_ws, size_t ws_size,
                              hipStream_t stream) {
  const float* x = (const float*)d_in[0];
  const float* y = (const float*)d_in[1];
  float* out = (float*)d_out;
  char* ws = (char*)d_ws;

  // ws layout (all regions fully written by producers; no memset needed):
  //   [0, 64KB)       hitpart: 256 blocks x 64 u32
  //   [64KB, +1KB)    sums_part: 256 f32
  //   [65KB, +1KB)    cnts_part: 256 f32
  //   [66KB, +2MB)    part: 4 qc x 131072 u32 embedded (d|idx)
  u32* hitpart = (u32*)ws;
  float* sums_part = (float*)(ws + 65536);
  float* cnts_part = (float*)(ws + 66560);
  u32* part = (u32*)(ws + 67584);

  nn_kernel<<<1024, 512, 0, stream>>>(x, y, part);
  merge_kernel<<<256, 512, 0, stream>>>(x, y, part, hitpart, sums_part, cnts_part);
  assemble_kernel<<<1, 512, 0, stream>>>(hitpart, sums_part, cnts_part, out);
}

// Round 15
// 90.569 us; speedup vs baseline: 1.2123x; 1.0118x over previous
//
#include <hip/hip_runtime.h>
#include <stdint.h>

// NormalizedLoss: batched chamfer + coverage/quality on point clouds.
// x: [32, 2048, 3] fp32, y: [32, 2048, 3] fp32 -> out: [val, cd, cov, qual] fp32.
//
// R15: REVERT to R11, the measured session optimum (90.9us). R12 (in-block
// consolidation, 91.8), R13 (MFMA, 109.8 - min/argmin epilogue is irreducibly
// VALU), R14 (P=8 half-LDS, 91.6) all failed to beat it; six structurally
// different nn kernels land in a 33-50us band with no pipe >65%, so R11's
// config is the empirical floor. Budget: ~41us harness ws-poison fill
// (268MB @ 82% achievable HBM, untouchable) + nn ~33 + merge ~4 + assemble
// ~3 + launch gaps ~8.
//
// nn: 1024 blocks (side|b|pc(3)|qc(1)) x 512 thr, P=4 per lane, q staged in
// LDS as pair-records, 8-wave q-split, 4 blocks/CU = 32 waves/CU (max TLP).
// Inner loop: v_pk_fma_f32 x3 + v_min3_f32 with 11-bit q-index embedded in
// the distance mantissa (EMB) -> single float carries (d, argmin) lex order.
// Truncation ~1e-3 << 1.2e-2 threshold.

#define BB 32
#define NP 2048
#define BIGF 1e10f

typedef unsigned int u32;
typedef float f2 __attribute__((ext_vector_type(2)));

// embed 11-bit global q-index in the mantissa: float order ~ (d, idx) lex
#define EMB(d, jg) __uint_as_float((__float_as_uint(d) & 0xFFFFF800u) | (jg))

__device__ __forceinline__ f2 pk_fma(f2 a, f2 b, f2 c) {
  f2 d;
  asm("v_pk_fma_f32 %0, %1, %2, %3" : "=v"(d) : "v"(a), "v"(b), "v"(c));
  return d;
}
__device__ __forceinline__ float min3(float a, float b, float c) {
  float r;
  asm("v_min3_f32 %0, %1, %2, %3" : "=v"(r) : "v"(a), "v"(b), "v"(c));
  return r;
}

__global__ __launch_bounds__(512, 8) void nn_kernel(const float* __restrict__ x,
                                                    const float* __restrict__ y,
                                                    u32* __restrict__ part) {
  int bid = blockIdx.x;  // 1024 blocks: side(1)|b(5)|pc(3)|qc(1)
  int side = bid >> 9;
  int b = (bid >> 4) & 31;
  int pc = (bid >> 1) & 7;
  int qc = bid & 1;
  int tid = threadIdx.x;
  int w = __builtin_amdgcn_readfirstlane(tid >> 6);  // 0..7, wave-uniform
  int lane = tid & 63;

  __shared__ float4 qs[1024];     // 16KB; rec r -> qs[2r]=(x0,x1,y0,y1), qs[2r+1]=(z0,z1,n0,n1)
  __shared__ u32 merged[8][256];  // 8KB per-wave embedded (d|idx) partials

  // ---- stage this block's 1024 q (qc half); 2 points per thread ----
  {
    const float* qraw = (side ? x : y) + (b * NP + qc * 1024) * 3 + tid * 6;
    f2 a01 = *(const f2*)(qraw);      // x0,y0
    f2 a23 = *(const f2*)(qraw + 2);  // z0,x1
    f2 a45 = *(const f2*)(qraw + 4);  // y1,z1
    float q0x = a01.x, q0y = a01.y, q0z = a23.x;
    float q1x = a23.y, q1y = a45.x, q1z = a45.y;
    float n0 = q0x * q0x + q0y * q0y + q0z * q0z;
    float n1 = q1x * q1x + q1y * q1y + q1z * q1z;
    if (q0x + q0y + q0z == 0.f) n0 += BIGF;  // invalid rows out of every min
    if (q1x + q1y + q1z == 0.f) n1 += BIGF;
    qs[2 * tid]     = make_float4(q0x, q1x, q0y, q1y);
    qs[2 * tid + 1] = make_float4(q0z, q1z, n0, n1);
  }

  // ---- p prologue: every wave loads the SAME 256 p; -2p dup'd into f2 ----
  const float* praw = (side ? y : x) + (b * NP + pc * 256) * 3;
  f2 pmx[4], pmy[4], pmz[4];
  float best[4];
#pragma unroll
  for (int k = 0; k < 4; ++k) {
    int pl = lane + 64 * k;
    float p0 = praw[3 * pl], p1 = praw[3 * pl + 1], p2 = praw[3 * pl + 2];
    pmx[k] = (f2){-2.f * p0, -2.f * p0};
    pmy[k] = (f2){-2.f * p1, -2.f * p1};
    pmz[k] = (f2){-2.f * p2, -2.f * p2};
    best[k] = 3.0e38f;
  }
  __syncthreads();

  // ---- inner loop: wave's 64 records (128 q) vs its 4 p-points ----
  const float4* qr = &qs[w * 128];
  u32 je = (u32)(qc * 1024 + w * 128);  // global q index of this wave's rec 0
#pragma unroll 8
  for (int r = 0; r < 64; ++r) {
    float4 A = qr[2 * r];      // wave-uniform ds_read_b128 (broadcast)
    float4 B = qr[2 * r + 1];
    f2 qx2 = (f2){A.x, A.y};
    f2 qy2 = (f2){A.z, A.w};
    f2 qz2 = (f2){B.x, B.y};
    f2 qw2 = (f2){B.z, B.w};
    u32 jg = je + 2 * (u32)r, jg1 = jg + 1;
#pragma unroll
    for (int k = 0; k < 4; ++k) {
      f2 d2 = pk_fma(qx2, pmx[k], pk_fma(qy2, pmy[k], pk_fma(qz2, pmz[k], qw2)));
      best[k] = min3(best[k], EMB(d2.x, jg), EMB(d2.y, jg1));
    }
  }

  merged[w][lane +   0] = __float_as_uint(best[0]);
  merged[w][lane +  64] = __float_as_uint(best[1]);
  merged[w][lane + 128] = __float_as_uint(best[2]);
  merged[w][lane + 192] = __float_as_uint(best[3]);
  __syncthreads();

  // ---- merge 8 wave partials; store embedded u32 per p ----
  if (tid < 256) {
    float bd = __uint_as_float(merged[0][tid]);
#pragma unroll
    for (int ww = 1; ww < 8; ++ww) bd = fminf(bd, __uint_as_float(merged[ww][tid]));
    // part[qc][side*65536 + b*2048 + pc*256 + tid]
    part[qc * 131072 + side * 65536 + b * 2048 + pc * 256 + tid] = __float_as_uint(bd);
  }
}

// 512 blocks x 256 thr: combine qc halves, recompute pn/validity, scatter
// hits into a block-local bitmask, reduce sums/cnts per block.
__global__ __launch_bounds__(256) void merge_kernel(const float* __restrict__ x,
                                                    const float* __restrict__ y,
                                                    const u32* __restrict__ part,
                                                    u32* __restrict__ hitpart,
                                                    float* __restrict__ sums_part,
                                                    float* __restrict__ cnts_part) {
  int bid = blockIdx.x;  // 512: side(1)|b(5)|pc(3)
  int side = bid >> 8;
  int b = (bid >> 3) & 31;
  int pc = bid & 7;
  int tid = threadIdx.x;
  int lane = tid & 63, w = tid >> 6;

  __shared__ u32 hitlds[64];
  __shared__ float redc[4], redn[4];
  if (tid < 64) hitlds[tid] = 0u;
  __syncthreads();

  int pidx = side * 65536 + b * 2048 + pc * 256 + tid;
  float bd = fminf(__uint_as_float(part[pidx]), __uint_as_float(part[131072 + pidx]));
  u32 bits = __float_as_uint(bd);
  u32 bi = bits & 0x7FFu;                            // global q index
  float dmin = __uint_as_float(bits & 0xFFFFF800u);  // truncated min d'
  const float* praw = (side ? y : x) + (b * NP + pc * 256 + tid) * 3;
  float p0 = praw[0], p1 = praw[1], p2 = praw[2];
  bool valid = (p0 + p1 + p2) != 0.f;
  float contrib = valid ? (dmin + p0 * p0 + p1 * p1 + p2 * p2) : 0.f;
  float cnt = valid ? 1.f : 0.f;
  if (valid) atomicOr(&hitlds[bi >> 5], 1u << (bi & 31));

  for (int o = 32; o > 0; o >>= 1) {
    contrib += __shfl_down(contrib, o, 64);
    cnt += __shfl_down(cnt, o, 64);
  }
  if (lane == 0) { redc[w] = contrib; redn[w] = cnt; }
  __syncthreads();
  if (tid == 0) {
    sums_part[bid] = redc[0] + redc[1] + redc[2] + redc[3];
    cnts_part[bid] = redn[0] + redn[1] + redn[2] + redn[3];
  }
  if (tid < 64) hitpart[bid * 64 + tid] = hitlds[tid];
}

// One block, 512 threads: 8 threads per (side,b); OR 8 pc-partials, popcount,
// sum part sums/cnts, then one wave assembles the 4 scalars.
__global__ __launch_bounds__(512) void assemble_kernel(const u32* __restrict__ hitpart,
                                                       const float* __restrict__ sums_part,
                                                       const float* __restrict__ cnts_part,
                                                       float* __restrict__ out) {
  __shared__ float hs[64], ss[64], cs[64];
  int tid = threadIdx.x;
  int sb = tid >> 3, c = tid & 7;  // sb = side*32+b; part bid = sb*8 + pc
  float h = 0.f;
  for (int wd = c; wd < 64; wd += 8) {
    u32 m = 0u;
#pragma unroll
    for (int blk = 0; blk < 8; ++blk) m |= hitpart[(sb * 8 + blk) * 64 + wd];
    h += (float)__popc(m);
  }
  h += __shfl_down(h, 4, 8);
  h += __shfl_down(h, 2, 8);
  h += __shfl_down(h, 1, 8);
  if (c == 0) {
    float s = 0.f, n = 0.f;
#pragma unroll
    for (int blk = 0; blk < 8; ++blk) {
      s += sums_part[sb * 8 + blk];
      n += cnts_part[sb * 8 + blk];
    }
    hs[sb] = h; ss[sb] = s; cs[sb] = n;
  }
  __syncthreads();
  if (tid < 64) {
    float cd = 0.f, cov = 0.f, qual = 0.f;
    if (tid < BB) {
      float nx = cs[tid], ny = cs[BB + tid];
      cd = ss[tid] / nx + ss[BB + tid] / ny;
      cov = hs[tid] / ny;        // side0 (p=x) hits y indices: /ny
      qual = hs[BB + tid] / nx;  // side1 (p=y) hits x indices: /nx
    }
    for (int o = 32; o > 0; o >>= 1) {
      cd += __shfl_down(cd, o, 64);
      cov += __shfl_down(cov, o, 64);
      qual += __shfl_down(qual, o, 64);
    }
    if (tid == 0) {
      cd /= (float)BB; cov /= (float)BB; qual /= (float)BB;
      out[0] = cd - 1e-4f * cov - 1e-4f * qual;  // WCD*cd - WCOV*cov - WQUAL*qual
      out[1] = cd;
      out[2] = cov;
      out[3] = qual;
    }
  }
}

extern "C" void kernel_launch(void* const* d_in, const int* in_sizes, int n_in,
                              void* d_out, int out_size, void* d_ws, size_t ws_size,
                              hipStream_t stream) {
  const float* x = (const float*)d_in[0];
  const float* y = (const float*)d_in[1];
  float* out = (float*)d_out;
  char* ws = (char*)d_ws;

  // ws layout (all regions fully written by producers; no memset needed):
  //   [0, 128KB)        hitpart: 512 blocks x 64 u32
  //   [128KB, +2KB)     sums_part: 512 f32
  //   [130KB, +2KB)     cnts_part: 512 f32
  //   [132KB, +1MB)     part: 2 qc x 131072 u32 embedded (d|idx)
  u32* hitpart = (u32*)ws;
  float* sums_part = (float*)(ws + 131072);
  float* cnts_part = (float*)(ws + 133120);
  u32* part = (u32*)(ws + 135168);

  nn_kernel<<<1024, 512, 0, stream>>>(x, y, part);
  merge_kernel<<<512, 256, 0, stream>>>(x, y, part, hitpart, sums_part, cnts_part);
  assemble_kernel<<<1, 512, 0, stream>>>(hitpart, sums_part, cnts_part, out);
}